// Round 5
// baseline (1324.899 us; speedup 1.0000x reference)
//
#include <hip/hip_runtime.h>

#define IN_SIZE 128
#define HID 256
#define N_SRC1 500000
#define N_DST1 100000
#define E1 1600000
#define N_DST2 16384
#define E2 262144

#define NB1 98   // ceil(100000/1024) buckets for layer-1 fill
#define NB2 16   // 16384/1024 buckets for layer-2 fill

// ---------------- workspace layout (bytes), total 162,377,216 ----------------
// xbf [500000][128] bf16 @ 0 (128,000,000)      live: prep -> gemm1
// h   [100000][256] bf16 @ 76,800,000 (51.2MB)  aliases xbf rows 300K..500K,
//                                               written by gemm1 (xbf tail dead)
// msg1 [100000][128] bf16 @ 128,000,000 (25.6MB)
// CSR + weights @ 153,600,000
#define OFF_XBF  0ull
#define OFF_H    76800000ull
#define OFF_MSG1 128000000ull
#define OFF_RP1  153600000ull   // [100001] i32 (400,128 alloc)
#define OFF_RP2  154000128ull   // [16385] i32  (65,664 alloc)
#define OFF_CUR1 154065792ull   // [100000] i32 (400,000)
#define OFF_CUR2 154465792ull   // [16384] i32  (65,536)   cur1+cur2 one memset
#define OFF_PRT1 154531328ull   // (2,048)
#define OFF_PRT2 154533376ull   // (2,048)
#define OFF_CSR1 154535424ull   // [1,600,000] i32 (6,400,000)
#define OFF_CSR2 160935424ull   // [262,144] i32 (1,048,576)
#define OFF_WP1  161984000ull   // packed W1 bf16 (131,072)
#define OFF_WP2  162115072ull   // packed W2 bf16 (262,144)

typedef __attribute__((ext_vector_type(8))) short short8;
typedef __attribute__((ext_vector_type(4))) float f32x4;

__device__ __forceinline__ unsigned short f2bf(float f) {
    unsigned u = __float_as_uint(f);
    return (unsigned short)((u + 0x7FFFu + ((u >> 16) & 1u)) >> 16);
}
__device__ __forceinline__ float bf2f(unsigned short b) {
    return __uint_as_float(((unsigned)b) << 16);
}

// ---------------- prep: cast x -> bf16, plus both histograms ----------------
__global__ __launch_bounds__(256) void k_prep(
    const float* __restrict__ x, unsigned short* __restrict__ xbf,
    const int* __restrict__ dst1, int* __restrict__ cur1,
    const int* __restrict__ dst2, int* __restrict__ cur2)
{
    const int T = gridDim.x * 256;
    const int tid = blockIdx.x * 256 + threadIdx.x;
    const float4* x4 = (const float4*)x;
    short8* o8 = (short8*)xbf;
    for (int i = tid; i < N_SRC1 * IN_SIZE / 8; i += T) {
        const float4 u0 = x4[(size_t)i * 2];
        const float4 u1 = x4[(size_t)i * 2 + 1];
        short8 o;
        o[0] = (short)f2bf(u0.x); o[1] = (short)f2bf(u0.y);
        o[2] = (short)f2bf(u0.z); o[3] = (short)f2bf(u0.w);
        o[4] = (short)f2bf(u1.x); o[5] = (short)f2bf(u1.y);
        o[6] = (short)f2bf(u1.z); o[7] = (short)f2bf(u1.w);
        o8[i] = o;
    }
    for (int e = tid; e < E1; e += T) atomicAdd(&cur1[dst1[e]], 1);
    for (int e = tid; e < E2; e += T) atomicAdd(&cur2[dst2[e]], 1);
}

// ---------------- CSR build: scans ----------------
__global__ __launch_bounds__(256) void k_scan_part(
    const int* __restrict__ cur1, int* __restrict__ prt1,
    const int* __restrict__ cur2, int* __restrict__ prt2, int nblk1)
{
    __shared__ int s[256];
    const int tid = threadIdx.x;
    const int l1 = (int)blockIdx.x < nblk1;
    const int b = l1 ? blockIdx.x : blockIdx.x - nblk1;
    const int n = l1 ? N_DST1 : N_DST2;
    const int* deg = l1 ? cur1 : cur2;
    int* part = l1 ? prt1 : prt2;
    const int gid = b * 256 + tid;
    s[tid] = (gid < n) ? deg[gid] : 0;
    __syncthreads();
    for (int off = 128; off > 0; off >>= 1) {
        if (tid < off) s[tid] += s[tid + off];
        __syncthreads();
    }
    if (tid == 0) part[b] = s[0];
}

__global__ __launch_bounds__(512) void k_scan_mid(
    int* __restrict__ prt1, int n1, int* __restrict__ prt2, int n2)
{
    __shared__ int s[512];
    int* p = (blockIdx.x == 0) ? prt1 : prt2;
    const int n = (blockIdx.x == 0) ? n1 : n2;
    const int tid = threadIdx.x;
    const int v = (tid < n) ? p[tid] : 0;
    s[tid] = v;
    __syncthreads();
    for (int off = 1; off < 512; off <<= 1) {
        int t = (tid >= off) ? s[tid - off] : 0;
        __syncthreads();
        s[tid] += t;
        __syncthreads();
    }
    if (tid < n) p[tid] = s[tid] - v;   // exclusive
}

__global__ __launch_bounds__(256) void k_scan_final(
    const int* __restrict__ cur1, int* __restrict__ rp1, const int* __restrict__ prt1,
    const int* __restrict__ cur2, int* __restrict__ rp2, const int* __restrict__ prt2,
    int nblk1)
{
    __shared__ int s[256];
    const int tid = threadIdx.x;
    const int l1 = (int)blockIdx.x < nblk1;
    const int b = l1 ? blockIdx.x : blockIdx.x - nblk1;
    const int n = l1 ? N_DST1 : N_DST2;
    const int* degcur = l1 ? cur1 : cur2;
    int* rowptr = l1 ? rp1 : rp2;
    const int* part = l1 ? prt1 : prt2;
    const int gid = b * 256 + tid;
    const int v = (gid < n) ? degcur[gid] : 0;
    s[tid] = v;
    __syncthreads();
    for (int off = 1; off < 256; off <<= 1) {
        int t = (tid >= off) ? s[tid - off] : 0;
        __syncthreads();
        s[tid] += t;
        __syncthreads();
    }
    const int base = part[b];
    if (gid < n) rowptr[gid] = base + s[tid] - v;
    if (gid == n - 1) rowptr[n] = base + s[tid];
}

// ---------------- bucketed CSR fill ----------------
// One block per 1024-dst bucket; cursors in LDS; csr writes go to the block's
// private contiguous region -> dense write-backs, no cross-XCD line sharing.
__global__ __launch_bounds__(256) void k_fill_bucket(
    const int* __restrict__ src1, const int* __restrict__ dst1,
    const int* __restrict__ rp1, int* __restrict__ csr1,
    const int* __restrict__ src2, const int* __restrict__ dst2,
    const int* __restrict__ rp2, int* __restrict__ csr2)
{
    __shared__ int lcur[1024];
    const int tid = threadIdx.x;
    const int l1 = (int)blockIdx.x < NB1;
    const int bkt = l1 ? blockIdx.x : blockIdx.x - NB1;
    const int base = bkt << 10;
    const int ndst = l1 ? N_DST1 : N_DST2;
    const int nrange = min(1024, ndst - base);
    const int* rp  = l1 ? rp1 : rp2;
    const int* src = l1 ? src1 : src2;
    const int* dst = l1 ? dst1 : dst2;
    int* csr = l1 ? csr1 : csr2;
    const int n4 = (l1 ? E1 : E2) >> 2;

    for (int i = tid; i < nrange; i += 256) lcur[i] = rp[base + i];
    __syncthreads();

    const int4* d4p = (const int4*)dst;
    for (int i = tid; i < n4; i += 256) {
        const int4 d4 = d4p[i];
        #pragma unroll
        for (int j = 0; j < 4; ++j) {
            const int d = (&d4.x)[j];
            const unsigned rel = (unsigned)(d - base);
            if (rel < 1024u) {
                const int pos = atomicAdd(&lcur[rel], 1);
                csr[pos] = src[i * 4 + j];
            }
        }
    }
}

// ---------------- weight packing ----------------
__global__ __launch_bounds__(256) void k_pack(const float* __restrict__ Wa,
                                              const float* __restrict__ Wb,
                                              int Keach, unsigned short* __restrict__ out) {
    const int t = blockIdx.x * 256 + threadIdx.x;
    const int total = (2 * Keach / 32) * 1024;
    if (t >= total) return;
    const int kb = t >> 10;
    const int c  = (t >> 2) & 255;
    const int g  = t & 3;
    const int kbase = kb * 32 + g * 8;
    const float* W = (kbase < Keach) ? (Wa + (size_t)kbase * HID + c)
                                     : (Wb + (size_t)(kbase - Keach) * HID + c);
    unsigned short* o = out + ((size_t)kb * 256 + c) * 32 + g * 8;
    #pragma unroll
    for (int j = 0; j < 8; ++j) o[j] = f2bf(W[(size_t)j * HID]);
}

// ---------------- layer-1 pull (bf16 gather, half-wave per dst) ----------------
__global__ __launch_bounds__(256) void k_pull1(
    const unsigned short* __restrict__ xbf, const int* __restrict__ rp,
    const int* __restrict__ csr, unsigned short* __restrict__ msg)
{
    const int d = blockIdx.x * 8 + (threadIdx.x >> 5);
    const int hl = threadIdx.x & 31;
    const int beg = rp[d], end = rp[d + 1];
    float a0 = 0.f, a1 = 0.f, a2 = 0.f, a3 = 0.f;
    const unsigned short* xb = xbf + hl * 4;
    int j = beg;
    for (; j + 3 < end; j += 4) {
        const int s0 = csr[j], s1 = csr[j + 1], s2 = csr[j + 2], s3 = csr[j + 3];
        const uint2 va = *(const uint2*)(xb + (size_t)s0 * IN_SIZE);
        const uint2 vb = *(const uint2*)(xb + (size_t)s1 * IN_SIZE);
        const uint2 vc = *(const uint2*)(xb + (size_t)s2 * IN_SIZE);
        const uint2 vd = *(const uint2*)(xb + (size_t)s3 * IN_SIZE);
        a0 += (bf2f(va.x) + bf2f(vb.x)) + (bf2f(vc.x) + bf2f(vd.x));
        a1 += (bf2f(va.x >> 16) + bf2f(vb.x >> 16)) + (bf2f(vc.x >> 16) + bf2f(vd.x >> 16));
        a2 += (bf2f(va.y) + bf2f(vb.y)) + (bf2f(vc.y) + bf2f(vd.y));
        a3 += (bf2f(va.y >> 16) + bf2f(vb.y >> 16)) + (bf2f(vc.y >> 16) + bf2f(vd.y >> 16));
    }
    for (; j < end; ++j) {
        const uint2 va = *(const uint2*)(xb + (size_t)csr[j] * IN_SIZE);
        a0 += bf2f(va.x); a1 += bf2f(va.x >> 16);
        a2 += bf2f(va.y); a3 += bf2f(va.y >> 16);
    }
    const float inv = 1.0f / fmaxf((float)(end - beg), 1.0f);
    uint2 o;
    o.x = (unsigned)f2bf(a0 * inv) | ((unsigned)f2bf(a1 * inv) << 16);
    o.y = (unsigned)f2bf(a2 * inv) | ((unsigned)f2bf(a3 * inv) << 16);
    *(uint2*)(msg + (size_t)d * IN_SIZE + hl * 4) = o;
}

// ---------------- layer-1 MFMA GEMM ----------------
__global__ __launch_bounds__(256) void k_gemm1(
    const unsigned short* __restrict__ A1,  // xbf [M][128]
    const unsigned short* __restrict__ A2,  // msg1 [M][128]
    const unsigned short* __restrict__ Wp,
    const float* __restrict__ bias,
    unsigned short* __restrict__ out)       // h bf16 [M][256]
{
    constexpr int NKS = 8;
    const int tid = threadIdx.x;
    const int wid = tid >> 6;
    const int lane = tid & 63;
    const int g = lane >> 4, r16 = lane & 15;
    const int i0 = blockIdx.x * 32;
    const int c0 = wid * 64;

    f32x4 acc[2][4];
    #pragma unroll
    for (int rb = 0; rb < 2; ++rb)
        #pragma unroll
        for (int cf = 0; cf < 4; ++cf)
            acc[rb][cf] = (f32x4){0.f, 0.f, 0.f, 0.f};

    #pragma unroll
    for (int ks = 0; ks < NKS; ++ks) {
        short8 a[2];
        #pragma unroll
        for (int rb = 0; rb < 2; ++rb) {
            const int row = i0 + rb * 16 + r16;
            const int kk = ks * 32 + g * 8;
            a[rb] = (ks < NKS / 2)
                ? *(const short8*)(A1 + (size_t)row * IN_SIZE + kk)
                : *(const short8*)(A2 + (size_t)row * IN_SIZE + (kk - IN_SIZE));
        }
        short8 b[4];
        #pragma unroll
        for (int cf = 0; cf < 4; ++cf) {
            const int col = c0 + cf * 16 + r16;
            b[cf] = *(const short8*)(Wp + ((size_t)ks * 256 + col) * 32 + g * 8);
        }
        #pragma unroll
        for (int rb = 0; rb < 2; ++rb)
            #pragma unroll
            for (int cf = 0; cf < 4; ++cf)
                acc[rb][cf] = __builtin_amdgcn_mfma_f32_16x16x32_bf16(
                    a[rb], b[cf], acc[rb][cf], 0, 0, 0);
    }

    #pragma unroll
    for (int cf = 0; cf < 4; ++cf) {
        const int col = c0 + cf * 16 + r16;
        const float bv = bias[col];
        #pragma unroll
        for (int rb = 0; rb < 2; ++rb)
            #pragma unroll
            for (int rr = 0; rr < 4; ++rr) {
                const int row = i0 + rb * 16 + g * 4 + rr;
                out[(size_t)row * HID + col] = f2bf(fmaxf(acc[rb][cf][rr] + bv, 0.0f));
            }
    }
}

// ---------------- layer-2 fused pull + MFMA GEMM ----------------
__global__ __launch_bounds__(256) void k_sage2(
    const unsigned short* __restrict__ h,   // [N_DST1][256] bf16
    const int* __restrict__ rp, const int* __restrict__ csr,
    const unsigned short* __restrict__ Wp,
    const float* __restrict__ bias,
    float* __restrict__ out)                // [N_DST2][256] f32
{
    __shared__ __align__(16) unsigned short At[32][264];
    const int tid = threadIdx.x;
    const int wid = tid >> 6;
    const int lane = tid & 63;
    const int i0 = blockIdx.x * 32;

    for (int r = 0; r < 8; ++r) {
        const int row = wid * 8 + r;
        const int d = i0 + row;
        const int beg = rp[d], end = rp[d + 1];
        float a0 = 0.f, a1 = 0.f, a2 = 0.f, a3 = 0.f;
        const unsigned short* hb = h + lane * 4;
        int j = beg;
        for (; j + 3 < end; j += 4) {
            const int s0 = csr[j], s1 = csr[j + 1], s2 = csr[j + 2], s3 = csr[j + 3];
            const uint2 va = *(const uint2*)(hb + (size_t)s0 * HID);
            const uint2 vb = *(const uint2*)(hb + (size_t)s1 * HID);
            const uint2 vc = *(const uint2*)(hb + (size_t)s2 * HID);
            const uint2 vd = *(const uint2*)(hb + (size_t)s3 * HID);
            a0 += (bf2f(va.x) + bf2f(vb.x)) + (bf2f(vc.x) + bf2f(vd.x));
            a1 += (bf2f(va.x >> 16) + bf2f(vb.x >> 16)) + (bf2f(vc.x >> 16) + bf2f(vd.x >> 16));
            a2 += (bf2f(va.y) + bf2f(vb.y)) + (bf2f(vc.y) + bf2f(vd.y));
            a3 += (bf2f(va.y >> 16) + bf2f(vb.y >> 16)) + (bf2f(vc.y >> 16) + bf2f(vd.y >> 16));
        }
        for (; j < end; ++j) {
            const uint2 va = *(const uint2*)(hb + (size_t)csr[j] * HID);
            a0 += bf2f(va.x); a1 += bf2f(va.x >> 16);
            a2 += bf2f(va.y); a3 += bf2f(va.y >> 16);
        }
        const float inv = 1.0f / fmaxf((float)(end - beg), 1.0f);
        uint2 o;
        o.x = (unsigned)f2bf(a0 * inv) | ((unsigned)f2bf(a1 * inv) << 16);
        o.y = (unsigned)f2bf(a2 * inv) | ((unsigned)f2bf(a3 * inv) << 16);
        *(uint2*)&At[row][lane * 4] = o;
    }
    __syncthreads();

    const int g = lane >> 4, r16 = lane & 15;
    const int c0 = wid * 64;
    f32x4 acc[2][4];
    #pragma unroll
    for (int rb = 0; rb < 2; ++rb)
        #pragma unroll
        for (int cf = 0; cf < 4; ++cf)
            acc[rb][cf] = (f32x4){0.f, 0.f, 0.f, 0.f};

    #pragma unroll
    for (int ks = 0; ks < 16; ++ks) {
        short8 a[2];
        #pragma unroll
        for (int rb = 0; rb < 2; ++rb) {
            const int row16 = rb * 16 + r16;
            if (ks < 8)
                a[rb] = *(const short8*)(h + (size_t)(i0 + row16) * HID + ks * 32 + g * 8);
            else
                a[rb] = *(const short8*)&At[row16][(ks - 8) * 32 + g * 8];
        }
        short8 b[4];
        #pragma unroll
        for (int cf = 0; cf < 4; ++cf) {
            const int col = c0 + cf * 16 + r16;
            b[cf] = *(const short8*)(Wp + ((size_t)ks * 256 + col) * 32 + g * 8);
        }
        #pragma unroll
        for (int rb = 0; rb < 2; ++rb)
            #pragma unroll
            for (int cf = 0; cf < 4; ++cf)
                acc[rb][cf] = __builtin_amdgcn_mfma_f32_16x16x32_bf16(
                    a[rb], b[cf], acc[rb][cf], 0, 0, 0);
    }

    #pragma unroll
    for (int cf = 0; cf < 4; ++cf) {
        const int col = c0 + cf * 16 + r16;
        const float bv = bias[col];
        #pragma unroll
        for (int rb = 0; rb < 2; ++rb)
            #pragma unroll
            for (int rr = 0; rr < 4; ++rr) {
                const int row = i0 + rb * 16 + g * 4 + rr;
                out[(size_t)row * HID + col] = acc[rb][cf][rr] + bv;
            }
    }
}

extern "C" void kernel_launch(void* const* d_in, const int* in_sizes, int n_in,
                              void* d_out, int out_size, void* d_ws, size_t ws_size,
                              hipStream_t stream) {
    const float* x       = (const float*)d_in[0];
    const int*   src1    = (const int*)d_in[1];
    const int*   dst1    = (const int*)d_in[2];
    const int*   src2    = (const int*)d_in[3];
    const int*   dst2    = (const int*)d_in[4];
    const float* W_self1 = (const float*)d_in[5];
    const float* W_neigh1= (const float*)d_in[6];
    const float* b1      = (const float*)d_in[7];
    const float* W_self2 = (const float*)d_in[8];
    const float* W_neigh2= (const float*)d_in[9];
    const float* b2      = (const float*)d_in[10];
    float* out = (float*)d_out;

    char* ws = (char*)d_ws;
    unsigned short* xbf  = (unsigned short*)(ws + OFF_XBF);
    unsigned short* h    = (unsigned short*)(ws + OFF_H);
    unsigned short* msg1 = (unsigned short*)(ws + OFF_MSG1);
    int* rp1  = (int*)(ws + OFF_RP1);
    int* rp2  = (int*)(ws + OFF_RP2);
    int* cur1 = (int*)(ws + OFF_CUR1);
    int* cur2 = (int*)(ws + OFF_CUR2);
    int* prt1 = (int*)(ws + OFF_PRT1);
    int* prt2 = (int*)(ws + OFF_PRT2);
    int* csr1 = (int*)(ws + OFF_CSR1);
    int* csr2 = (int*)(ws + OFF_CSR2);
    unsigned short* wp1 = (unsigned short*)(ws + OFF_WP1);
    unsigned short* wp2 = (unsigned short*)(ws + OFF_WP2);

    const int nblk1 = (N_DST1 + 255) / 256;   // 391
    const int nblk2 = (N_DST2 + 255) / 256;   // 64

    hipMemsetAsync(cur1, 0, 465536, stream);

    k_pack<<<32, 256, 0, stream>>>(W_self1, W_neigh1, 128, wp1);
    k_pack<<<64, 256, 0, stream>>>(W_self2, W_neigh2, 256, wp2);

    k_prep<<<2048, 256, 0, stream>>>(x, xbf, dst1, cur1, dst2, cur2);
    k_scan_part<<<nblk1 + nblk2, 256, 0, stream>>>(cur1, prt1, cur2, prt2, nblk1);
    k_scan_mid<<<2, 512, 0, stream>>>(prt1, nblk1, prt2, nblk2);
    k_scan_final<<<nblk1 + nblk2, 256, 0, stream>>>(cur1, rp1, prt1, cur2, rp2, prt2, nblk1);
    k_fill_bucket<<<NB1 + NB2, 256, 0, stream>>>(src1, dst1, rp1, csr1,
                                                 src2, dst2, rp2, csr2);

    k_pull1<<<N_DST1 / 8, 256, 0, stream>>>(xbf, rp1, csr1, msg1);
    k_gemm1<<<N_DST1 / 32, 256, 0, stream>>>(xbf, msg1, wp1, b1, h);
    k_sage2<<<N_DST2 / 32, 256, 0, stream>>>(h, rp2, csr2, wp2, b2, out);
}

// Round 6
// 850.195 us; speedup vs baseline: 1.5583x; 1.5583x over previous
//
#include <hip/hip_runtime.h>

#define IN_SIZE 128
#define HID 256
#define N_SRC1 500000
#define N_DST1 100000
#define E1 1600000
#define N_DST2 16384
#define E2 262144

// radix fill parameters: bins of 512 dst
#define NBIN1 196          // ceil(100000/512)
#define NBIN2 32           // 16384/512
#define FCAP  64           // LDS FIFO capacity per bin
#define P1B1  512          // phase-1 blocks layer 1 (E1/512 = 3125 edges each)
#define P1B2  256          // phase-1 blocks layer 2 (E2/256 = 1024 edges each)

// ---------------- workspace layout (bytes) ----------------
// xbf [500000][128] bf16 @ 0 (128,000,000)      live: prep -> gemm1
// h   [100000][256] bf16 @ 76,800,000 (51.2MB)  aliases xbf rows 300K..500K
// msg1 [100000][128] bf16 @ 128,000,000 (25.6MB)
//   stage1 [1.6M] u32 @ 128,000,000 (6.4MB)   live: fill_p1 -> fill_p2 (pre-pull1)
//   stage2 [262144] u32 @ 134,400,000 (1.05MB)
// CSR + weights @ 153,600,000; gcur @ 162,377,216; total 162,378,240
#define OFF_XBF  0ull
#define OFF_H    76800000ull
#define OFF_MSG1 128000000ull
#define OFF_STG1 128000000ull
#define OFF_STG2 134400000ull
#define OFF_RP1  153600000ull   // [100001] i32 (400,128 alloc)
#define OFF_RP2  154000128ull   // [16385] i32  (65,664 alloc)
#define OFF_CUR1 154065792ull   // [100000] i32 (400,000)
#define OFF_CUR2 154465792ull   // [16384] i32  (65,536)   cur1+cur2 one memset
#define OFF_PRT1 154531328ull   // (2,048)
#define OFF_PRT2 154533376ull   // (2,048)
#define OFF_CSR1 154535424ull   // [1,600,000] i32 (6,400,000)
#define OFF_CSR2 160935424ull   // [262,144] i32 (1,048,576)
#define OFF_WP1  161984000ull   // packed W1 bf16 (131,072)
#define OFF_WP2  162115072ull   // packed W2 bf16 (262,144)
#define OFF_GCUR 162377216ull   // [NBIN1+NBIN2] i32 (1,024 alloc)

typedef __attribute__((ext_vector_type(8))) short short8;
typedef __attribute__((ext_vector_type(4))) float f32x4;

__device__ __forceinline__ unsigned short f2bf(float f) {
    unsigned u = __float_as_uint(f);
    return (unsigned short)((u + 0x7FFFu + ((u >> 16) & 1u)) >> 16);
}
__device__ __forceinline__ float bf2f(unsigned short b) {
    return __uint_as_float(((unsigned)b) << 16);
}

// ---------------- prep: cast x -> bf16, plus both histograms ----------------
__global__ __launch_bounds__(256) void k_prep(
    const float* __restrict__ x, unsigned short* __restrict__ xbf,
    const int* __restrict__ dst1, int* __restrict__ cur1,
    const int* __restrict__ dst2, int* __restrict__ cur2)
{
    const int T = gridDim.x * 256;
    const int tid = blockIdx.x * 256 + threadIdx.x;
    const float4* x4 = (const float4*)x;
    short8* o8 = (short8*)xbf;
    for (int i = tid; i < N_SRC1 * IN_SIZE / 8; i += T) {
        const float4 u0 = x4[(size_t)i * 2];
        const float4 u1 = x4[(size_t)i * 2 + 1];
        short8 o;
        o[0] = (short)f2bf(u0.x); o[1] = (short)f2bf(u0.y);
        o[2] = (short)f2bf(u0.z); o[3] = (short)f2bf(u0.w);
        o[4] = (short)f2bf(u1.x); o[5] = (short)f2bf(u1.y);
        o[6] = (short)f2bf(u1.z); o[7] = (short)f2bf(u1.w);
        o8[i] = o;
    }
    for (int e = tid; e < E1; e += T) atomicAdd(&cur1[dst1[e]], 1);
    for (int e = tid; e < E2; e += T) atomicAdd(&cur2[dst2[e]], 1);
}

// ---------------- CSR build: scans ----------------
__global__ __launch_bounds__(256) void k_scan_part(
    const int* __restrict__ cur1, int* __restrict__ prt1,
    const int* __restrict__ cur2, int* __restrict__ prt2, int nblk1)
{
    __shared__ int s[256];
    const int tid = threadIdx.x;
    const int l1 = (int)blockIdx.x < nblk1;
    const int b = l1 ? blockIdx.x : blockIdx.x - nblk1;
    const int n = l1 ? N_DST1 : N_DST2;
    const int* deg = l1 ? cur1 : cur2;
    int* part = l1 ? prt1 : prt2;
    const int gid = b * 256 + tid;
    s[tid] = (gid < n) ? deg[gid] : 0;
    __syncthreads();
    for (int off = 128; off > 0; off >>= 1) {
        if (tid < off) s[tid] += s[tid + off];
        __syncthreads();
    }
    if (tid == 0) part[b] = s[0];
}

__global__ __launch_bounds__(512) void k_scan_mid(
    int* __restrict__ prt1, int n1, int* __restrict__ prt2, int n2)
{
    __shared__ int s[512];
    int* p = (blockIdx.x == 0) ? prt1 : prt2;
    const int n = (blockIdx.x == 0) ? n1 : n2;
    const int tid = threadIdx.x;
    const int v = (tid < n) ? p[tid] : 0;
    s[tid] = v;
    __syncthreads();
    for (int off = 1; off < 512; off <<= 1) {
        int t = (tid >= off) ? s[tid - off] : 0;
        __syncthreads();
        s[tid] += t;
        __syncthreads();
    }
    if (tid < n) p[tid] = s[tid] - v;   // exclusive
}

__global__ __launch_bounds__(256) void k_scan_final(
    const int* __restrict__ cur1, int* __restrict__ rp1, const int* __restrict__ prt1,
    const int* __restrict__ cur2, int* __restrict__ rp2, const int* __restrict__ prt2,
    int nblk1)
{
    __shared__ int s[256];
    const int tid = threadIdx.x;
    const int l1 = (int)blockIdx.x < nblk1;
    const int b = l1 ? blockIdx.x : blockIdx.x - nblk1;
    const int n = l1 ? N_DST1 : N_DST2;
    const int* degcur = l1 ? cur1 : cur2;
    int* rowptr = l1 ? rp1 : rp2;
    const int* part = l1 ? prt1 : prt2;
    const int gid = b * 256 + tid;
    const int v = (gid < n) ? degcur[gid] : 0;
    s[tid] = v;
    __syncthreads();
    for (int off = 1; off < 256; off <<= 1) {
        int t = (tid >= off) ? s[tid - off] : 0;
        __syncthreads();
        s[tid] += t;
        __syncthreads();
    }
    const int base = part[b];
    if (gid < n) rowptr[gid] = base + s[tid] - v;
    if (gid == n - 1) rowptr[n] = base + s[tid];
}

// init per-bin global cursors from rowptr (bins of 512 dst)
__global__ void k_init_gcur(const int* __restrict__ rp1,
                            const int* __restrict__ rp2, int* __restrict__ gcur) {
    const int t = threadIdx.x;
    if (t < NBIN1) gcur[t] = rp1[t << 9];
    else if (t < NBIN1 + NBIN2) gcur[t - NBIN1 + NBIN1] = rp2[(t - NBIN1) << 9];
}

// ---------------- radix fill phase 1: edge-parallel binning ----------------
// Pack (dst&511)<<19 | src into u32 (src < 2^19); bin by dst>>9 into LDS
// FIFOs; flush runs to the bin's staging region (= rowptr-sized, exact fit)
// with one global-atomic reservation per (block,bin). Cap overflow -> correct
// per-entry slow path.
__global__ __launch_bounds__(256) void k_fill_p1(
    const int* __restrict__ src1, const int* __restrict__ dst1,
    unsigned* __restrict__ stage1,
    const int* __restrict__ src2, const int* __restrict__ dst2,
    unsigned* __restrict__ stage2,
    int* __restrict__ gcur)
{
    __shared__ unsigned lbuf[NBIN1 * FCAP];
    __shared__ int lcnt[NBIN1];
    const int tid = threadIdx.x;
    const bool l1 = blockIdx.x < P1B1;
    const int nbins = l1 ? NBIN1 : NBIN2;
    const int chunk = l1 ? (E1 / P1B1) : (E2 / P1B2);
    const int e0 = (l1 ? blockIdx.x : (blockIdx.x - P1B1)) * chunk;
    const int* src = l1 ? src1 : src2;
    const int* dst = l1 ? dst1 : dst2;
    unsigned* stage = l1 ? stage1 : stage2;
    int* gc = gcur + (l1 ? 0 : NBIN1);

    for (int i = tid; i < nbins; i += 256) lcnt[i] = 0;
    __syncthreads();

    for (int i = tid; i < chunk; i += 256) {
        const int e = e0 + i;
        const int d = dst[e];
        const unsigned pk = ((unsigned)(d & 511) << 19) | (unsigned)src[e];
        const int bin = d >> 9;
        const int slot = atomicAdd(&lcnt[bin], 1);
        if (slot < FCAP) lbuf[bin * FCAP + slot] = pk;
        else stage[atomicAdd(&gc[bin], 1)] = pk;   // rare slow path
    }
    __syncthreads();

    const int wid = tid >> 6, lane = tid & 63;
    for (int bin = wid; bin < nbins; bin += 4) {
        const int cnt = min(lcnt[bin], FCAP);
        if (cnt == 0) continue;
        int gp;
        if (lane == 0) gp = atomicAdd(&gc[bin], cnt);
        gp = __shfl(gp, 0);
        for (int t = lane; t < cnt; t += 64)
            stage[gp + t] = lbuf[bin * FCAP + t];
    }
}

// ---------------- radix fill phase 2: per-bin local counting sort ----------------
// One block per bin; cursors in LDS; reads its staged entries coalesced;
// writes csr into its private window -> dense, single-owner write-backs.
__global__ __launch_bounds__(256) void k_fill_p2(
    const unsigned* __restrict__ stage1, const int* __restrict__ rp1, int* __restrict__ csr1,
    const unsigned* __restrict__ stage2, const int* __restrict__ rp2, int* __restrict__ csr2)
{
    __shared__ int lcur[512];
    const int tid = threadIdx.x;
    const bool l1 = blockIdx.x < NBIN1;
    const int b = l1 ? blockIdx.x : blockIdx.x - NBIN1;
    const int base = b << 9;
    const int ndst = l1 ? N_DST1 : N_DST2;
    const int nr = min(512, ndst - base);
    const int* rp = l1 ? rp1 : rp2;
    const unsigned* stage = l1 ? stage1 : stage2;
    int* csr = l1 ? csr1 : csr2;

    for (int i = tid; i < nr; i += 256) lcur[i] = rp[base + i];
    __syncthreads();
    const int s0 = rp[base], s1 = rp[base + nr];
    for (int i = s0 + tid; i < s1; i += 256) {
        const unsigned pk = stage[i];
        const int pos = atomicAdd(&lcur[pk >> 19], 1);
        csr[pos] = (int)(pk & 0x7FFFFu);
    }
}

// ---------------- weight packing ----------------
__global__ __launch_bounds__(256) void k_pack(const float* __restrict__ Wa,
                                              const float* __restrict__ Wb,
                                              int Keach, unsigned short* __restrict__ out) {
    const int t = blockIdx.x * 256 + threadIdx.x;
    const int total = (2 * Keach / 32) * 1024;
    if (t >= total) return;
    const int kb = t >> 10;
    const int c  = (t >> 2) & 255;
    const int g  = t & 3;
    const int kbase = kb * 32 + g * 8;
    const float* W = (kbase < Keach) ? (Wa + (size_t)kbase * HID + c)
                                     : (Wb + (size_t)(kbase - Keach) * HID + c);
    unsigned short* o = out + ((size_t)kb * 256 + c) * 32 + g * 8;
    #pragma unroll
    for (int j = 0; j < 8; ++j) o[j] = f2bf(W[(size_t)j * HID]);
}

// ---------------- layer-1 pull (bf16 gather, half-wave per dst) ----------------
__global__ __launch_bounds__(256) void k_pull1(
    const unsigned short* __restrict__ xbf, const int* __restrict__ rp,
    const int* __restrict__ csr, unsigned short* __restrict__ msg)
{
    const int d = blockIdx.x * 8 + (threadIdx.x >> 5);
    const int hl = threadIdx.x & 31;
    const int beg = rp[d], end = rp[d + 1];
    float a0 = 0.f, a1 = 0.f, a2 = 0.f, a3 = 0.f;
    const unsigned short* xb = xbf + hl * 4;
    int j = beg;
    for (; j + 3 < end; j += 4) {
        const int s0 = csr[j], s1 = csr[j + 1], s2 = csr[j + 2], s3 = csr[j + 3];
        const uint2 va = *(const uint2*)(xb + (size_t)s0 * IN_SIZE);
        const uint2 vb = *(const uint2*)(xb + (size_t)s1 * IN_SIZE);
        const uint2 vc = *(const uint2*)(xb + (size_t)s2 * IN_SIZE);
        const uint2 vd = *(const uint2*)(xb + (size_t)s3 * IN_SIZE);
        a0 += (bf2f(va.x) + bf2f(vb.x)) + (bf2f(vc.x) + bf2f(vd.x));
        a1 += (bf2f(va.x >> 16) + bf2f(vb.x >> 16)) + (bf2f(vc.x >> 16) + bf2f(vd.x >> 16));
        a2 += (bf2f(va.y) + bf2f(vb.y)) + (bf2f(vc.y) + bf2f(vd.y));
        a3 += (bf2f(va.y >> 16) + bf2f(vb.y >> 16)) + (bf2f(vc.y >> 16) + bf2f(vd.y >> 16));
    }
    for (; j < end; ++j) {
        const uint2 va = *(const uint2*)(xb + (size_t)csr[j] * IN_SIZE);
        a0 += bf2f(va.x); a1 += bf2f(va.x >> 16);
        a2 += bf2f(va.y); a3 += bf2f(va.y >> 16);
    }
    const float inv = 1.0f / fmaxf((float)(end - beg), 1.0f);
    uint2 o;
    o.x = (unsigned)f2bf(a0 * inv) | ((unsigned)f2bf(a1 * inv) << 16);
    o.y = (unsigned)f2bf(a2 * inv) | ((unsigned)f2bf(a3 * inv) << 16);
    *(uint2*)(msg + (size_t)d * IN_SIZE + hl * 4) = o;
}

// ---------------- layer-1 MFMA GEMM ----------------
__global__ __launch_bounds__(256) void k_gemm1(
    const unsigned short* __restrict__ A1,  // xbf [M][128]
    const unsigned short* __restrict__ A2,  // msg1 [M][128]
    const unsigned short* __restrict__ Wp,
    const float* __restrict__ bias,
    unsigned short* __restrict__ out)       // h bf16 [M][256]
{
    constexpr int NKS = 8;
    const int tid = threadIdx.x;
    const int wid = tid >> 6;
    const int lane = tid & 63;
    const int g = lane >> 4, r16 = lane & 15;
    const int i0 = blockIdx.x * 32;
    const int c0 = wid * 64;

    f32x4 acc[2][4];
    #pragma unroll
    for (int rb = 0; rb < 2; ++rb)
        #pragma unroll
        for (int cf = 0; cf < 4; ++cf)
            acc[rb][cf] = (f32x4){0.f, 0.f, 0.f, 0.f};

    #pragma unroll
    for (int ks = 0; ks < NKS; ++ks) {
        short8 a[2];
        #pragma unroll
        for (int rb = 0; rb < 2; ++rb) {
            const int row = i0 + rb * 16 + r16;
            const int kk = ks * 32 + g * 8;
            a[rb] = (ks < NKS / 2)
                ? *(const short8*)(A1 + (size_t)row * IN_SIZE + kk)
                : *(const short8*)(A2 + (size_t)row * IN_SIZE + (kk - IN_SIZE));
        }
        short8 b[4];
        #pragma unroll
        for (int cf = 0; cf < 4; ++cf) {
            const int col = c0 + cf * 16 + r16;
            b[cf] = *(const short8*)(Wp + ((size_t)ks * 256 + col) * 32 + g * 8);
        }
        #pragma unroll
        for (int rb = 0; rb < 2; ++rb)
            #pragma unroll
            for (int cf = 0; cf < 4; ++cf)
                acc[rb][cf] = __builtin_amdgcn_mfma_f32_16x16x32_bf16(
                    a[rb], b[cf], acc[rb][cf], 0, 0, 0);
    }

    #pragma unroll
    for (int cf = 0; cf < 4; ++cf) {
        const int col = c0 + cf * 16 + r16;
        const float bv = bias[col];
        #pragma unroll
        for (int rb = 0; rb < 2; ++rb)
            #pragma unroll
            for (int rr = 0; rr < 4; ++rr) {
                const int row = i0 + rb * 16 + g * 4 + rr;
                out[(size_t)row * HID + col] = f2bf(fmaxf(acc[rb][cf][rr] + bv, 0.0f));
            }
    }
}

// ---------------- layer-2 fused pull + MFMA GEMM ----------------
__global__ __launch_bounds__(256) void k_sage2(
    const unsigned short* __restrict__ h,   // [N_DST1][256] bf16
    const int* __restrict__ rp, const int* __restrict__ csr,
    const unsigned short* __restrict__ Wp,
    const float* __restrict__ bias,
    float* __restrict__ out)                // [N_DST2][256] f32
{
    __shared__ __align__(16) unsigned short At[32][264];
    const int tid = threadIdx.x;
    const int wid = tid >> 6;
    const int lane = tid & 63;
    const int i0 = blockIdx.x * 32;

    for (int r = 0; r < 8; ++r) {
        const int row = wid * 8 + r;
        const int d = i0 + row;
        const int beg = rp[d], end = rp[d + 1];
        float a0 = 0.f, a1 = 0.f, a2 = 0.f, a3 = 0.f;
        const unsigned short* hb = h + lane * 4;
        int j = beg;
        for (; j + 3 < end; j += 4) {
            const int s0 = csr[j], s1 = csr[j + 1], s2 = csr[j + 2], s3 = csr[j + 3];
            const uint2 va = *(const uint2*)(hb + (size_t)s0 * HID);
            const uint2 vb = *(const uint2*)(hb + (size_t)s1 * HID);
            const uint2 vc = *(const uint2*)(hb + (size_t)s2 * HID);
            const uint2 vd = *(const uint2*)(hb + (size_t)s3 * HID);
            a0 += (bf2f(va.x) + bf2f(vb.x)) + (bf2f(vc.x) + bf2f(vd.x));
            a1 += (bf2f(va.x >> 16) + bf2f(vb.x >> 16)) + (bf2f(vc.x >> 16) + bf2f(vd.x >> 16));
            a2 += (bf2f(va.y) + bf2f(vb.y)) + (bf2f(vc.y) + bf2f(vd.y));
            a3 += (bf2f(va.y >> 16) + bf2f(vb.y >> 16)) + (bf2f(vc.y >> 16) + bf2f(vd.y >> 16));
        }
        for (; j < end; ++j) {
            const uint2 va = *(const uint2*)(hb + (size_t)csr[j] * HID);
            a0 += bf2f(va.x); a1 += bf2f(va.x >> 16);
            a2 += bf2f(va.y); a3 += bf2f(va.y >> 16);
        }
        const float inv = 1.0f / fmaxf((float)(end - beg), 1.0f);
        uint2 o;
        o.x = (unsigned)f2bf(a0 * inv) | ((unsigned)f2bf(a1 * inv) << 16);
        o.y = (unsigned)f2bf(a2 * inv) | ((unsigned)f2bf(a3 * inv) << 16);
        *(uint2*)&At[row][lane * 4] = o;
    }
    __syncthreads();

    const int g = lane >> 4, r16 = lane & 15;
    const int c0 = wid * 64;
    f32x4 acc[2][4];
    #pragma unroll
    for (int rb = 0; rb < 2; ++rb)
        #pragma unroll
        for (int cf = 0; cf < 4; ++cf)
            acc[rb][cf] = (f32x4){0.f, 0.f, 0.f, 0.f};

    #pragma unroll
    for (int ks = 0; ks < 16; ++ks) {
        short8 a[2];
        #pragma unroll
        for (int rb = 0; rb < 2; ++rb) {
            const int row16 = rb * 16 + r16;
            if (ks < 8)
                a[rb] = *(const short8*)(h + (size_t)(i0 + row16) * HID + ks * 32 + g * 8);
            else
                a[rb] = *(const short8*)&At[row16][(ks - 8) * 32 + g * 8];
        }
        short8 b[4];
        #pragma unroll
        for (int cf = 0; cf < 4; ++cf) {
            const int col = c0 + cf * 16 + r16;
            b[cf] = *(const short8*)(Wp + ((size_t)ks * 256 + col) * 32 + g * 8);
        }
        #pragma unroll
        for (int rb = 0; rb < 2; ++rb)
            #pragma unroll
            for (int cf = 0; cf < 4; ++cf)
                acc[rb][cf] = __builtin_amdgcn_mfma_f32_16x16x32_bf16(
                    a[rb], b[cf], acc[rb][cf], 0, 0, 0);
    }

    #pragma unroll
    for (int cf = 0; cf < 4; ++cf) {
        const int col = c0 + cf * 16 + r16;
        const float bv = bias[col];
        #pragma unroll
        for (int rb = 0; rb < 2; ++rb)
            #pragma unroll
            for (int rr = 0; rr < 4; ++rr) {
                const int row = i0 + rb * 16 + g * 4 + rr;
                out[(size_t)row * HID + col] = acc[rb][cf][rr] + bv;
            }
    }
}

extern "C" void kernel_launch(void* const* d_in, const int* in_sizes, int n_in,
                              void* d_out, int out_size, void* d_ws, size_t ws_size,
                              hipStream_t stream) {
    const float* x       = (const float*)d_in[0];
    const int*   src1    = (const int*)d_in[1];
    const int*   dst1    = (const int*)d_in[2];
    const int*   src2    = (const int*)d_in[3];
    const int*   dst2    = (const int*)d_in[4];
    const float* W_self1 = (const float*)d_in[5];
    const float* W_neigh1= (const float*)d_in[6];
    const float* b1      = (const float*)d_in[7];
    const float* W_self2 = (const float*)d_in[8];
    const float* W_neigh2= (const float*)d_in[9];
    const float* b2      = (const float*)d_in[10];
    float* out = (float*)d_out;

    char* ws = (char*)d_ws;
    unsigned short* xbf  = (unsigned short*)(ws + OFF_XBF);
    unsigned short* h    = (unsigned short*)(ws + OFF_H);
    unsigned short* msg1 = (unsigned short*)(ws + OFF_MSG1);
    unsigned* stg1 = (unsigned*)(ws + OFF_STG1);
    unsigned* stg2 = (unsigned*)(ws + OFF_STG2);
    int* rp1  = (int*)(ws + OFF_RP1);
    int* rp2  = (int*)(ws + OFF_RP2);
    int* cur1 = (int*)(ws + OFF_CUR1);
    int* cur2 = (int*)(ws + OFF_CUR2);
    int* prt1 = (int*)(ws + OFF_PRT1);
    int* prt2 = (int*)(ws + OFF_PRT2);
    int* csr1 = (int*)(ws + OFF_CSR1);
    int* csr2 = (int*)(ws + OFF_CSR2);
    unsigned short* wp1 = (unsigned short*)(ws + OFF_WP1);
    unsigned short* wp2 = (unsigned short*)(ws + OFF_WP2);
    int* gcur = (int*)(ws + OFF_GCUR);

    const int nblk1 = (N_DST1 + 255) / 256;   // 391
    const int nblk2 = (N_DST2 + 255) / 256;   // 64

    hipMemsetAsync(cur1, 0, 465536, stream);

    k_pack<<<32, 256, 0, stream>>>(W_self1, W_neigh1, 128, wp1);
    k_pack<<<64, 256, 0, stream>>>(W_self2, W_neigh2, 256, wp2);

    k_prep<<<2048, 256, 0, stream>>>(x, xbf, dst1, cur1, dst2, cur2);
    k_scan_part<<<nblk1 + nblk2, 256, 0, stream>>>(cur1, prt1, cur2, prt2, nblk1);
    k_scan_mid<<<2, 512, 0, stream>>>(prt1, nblk1, prt2, nblk2);
    k_scan_final<<<nblk1 + nblk2, 256, 0, stream>>>(cur1, rp1, prt1, cur2, rp2, prt2, nblk1);
    k_init_gcur<<<1, 256, 0, stream>>>(rp1, rp2, gcur);
    k_fill_p1<<<P1B1 + P1B2, 256, 0, stream>>>(src1, dst1, stg1, src2, dst2, stg2, gcur);
    k_fill_p2<<<NBIN1 + NBIN2, 256, 0, stream>>>(stg1, rp1, csr1, stg2, rp2, csr2);

    k_pull1<<<N_DST1 / 8, 256, 0, stream>>>(xbf, rp1, csr1, msg1);
    k_gemm1<<<N_DST1 / 32, 256, 0, stream>>>(xbf, msg1, wp1, b1, h);
    k_sage2<<<N_DST2 / 32, 256, 0, stream>>>(h, rp2, csr2, wp2, b2, out);
}

// Round 7
// 372.417 us; speedup vs baseline: 3.5576x; 2.2829x over previous
//
#include <hip/hip_runtime.h>

#define IN_SIZE 128
#define HID 256
#define N_SRC1 500000
#define N_DST1 100000
#define E1 1600000
#define N_DST2 16384
#define E2 262144

// radix fill: bins of 512 dst, atomic-free 3-phase (hist -> scan -> place)
#define NBIN1 196          // ceil(100000/512)
#define NBIN2 32           // 16384/512
#define P1B1  800          // layer-1 blocks, chunk = E1/800 = 2000 edges
#define P1B2  256          // layer-2 blocks, chunk = E2/256 = 1024 edges

// ---------------- workspace layout (bytes) ----------------
// xbf [500000][128] bf16 @ 0 (128,000,000)      live: prep -> gemm1
// h   [100000][256] bf16 @ 76,800,000 (51.2MB)  aliases xbf rows 300K..500K
// msg1 [100000][128] bf16 @ 128,000,000 (25.6MB) live: pull1 -> gemm1
//   fill scratch lives INSIDE msg1 (dead before pull1 writes msg1):
//     stg1 [1.6M] u32 @ +0 (6.4MB), stg2 @ +6.4M (1.05MB)
//     hist1 [800][196] @ +7,448,576 (627,200), offs1 @ +8,075,776
//     hist2 [256][32]  @ +8,702,976 (32,768),  offs2 @ +8,735,744
// CSR + weights @ 153,600,000; total 162,377,216
#define OFF_XBF  0ull
#define OFF_H    76800000ull
#define OFF_MSG1 128000000ull
#define OFF_STG1 128000000ull
#define OFF_STG2 134400000ull
#define OFF_HIST1 135448576ull
#define OFF_OFFS1 136075776ull
#define OFF_HIST2 136702976ull
#define OFF_OFFS2 136735744ull
#define OFF_RP1  153600000ull   // [100001] i32 (400,128 alloc)
#define OFF_RP2  154000128ull   // [16385] i32  (65,664 alloc)
#define OFF_CUR1 154065792ull   // [100000] i32 (400,000)
#define OFF_CUR2 154465792ull   // [16384] i32  (65,536)   cur1+cur2 one memset
#define OFF_PRT1 154531328ull   // (2,048)
#define OFF_PRT2 154533376ull   // (2,048)
#define OFF_CSR1 154535424ull   // [1,600,000] i32 (6,400,000)
#define OFF_CSR2 160935424ull   // [262,144] i32 (1,048,576)
#define OFF_WP1  161984000ull   // packed W1 bf16 (131,072)
#define OFF_WP2  162115072ull   // packed W2 bf16 (262,144)

typedef __attribute__((ext_vector_type(8))) short short8;
typedef __attribute__((ext_vector_type(4))) float f32x4;

__device__ __forceinline__ unsigned short f2bf(float f) {
    unsigned u = __float_as_uint(f);
    return (unsigned short)((u + 0x7FFFu + ((u >> 16) & 1u)) >> 16);
}
__device__ __forceinline__ float bf2f(unsigned short b) {
    return __uint_as_float(((unsigned)b) << 16);
}

// ---------------- prep: cast x -> bf16, plus both degree histograms ----------------
__global__ __launch_bounds__(256) void k_prep(
    const float* __restrict__ x, unsigned short* __restrict__ xbf,
    const int* __restrict__ dst1, int* __restrict__ cur1,
    const int* __restrict__ dst2, int* __restrict__ cur2)
{
    const int T = gridDim.x * 256;
    const int tid = blockIdx.x * 256 + threadIdx.x;
    const float4* x4 = (const float4*)x;
    short8* o8 = (short8*)xbf;
    for (int i = tid; i < N_SRC1 * IN_SIZE / 8; i += T) {
        const float4 u0 = x4[(size_t)i * 2];
        const float4 u1 = x4[(size_t)i * 2 + 1];
        short8 o;
        o[0] = (short)f2bf(u0.x); o[1] = (short)f2bf(u0.y);
        o[2] = (short)f2bf(u0.z); o[3] = (short)f2bf(u0.w);
        o[4] = (short)f2bf(u1.x); o[5] = (short)f2bf(u1.y);
        o[6] = (short)f2bf(u1.z); o[7] = (short)f2bf(u1.w);
        o8[i] = o;
    }
    for (int e = tid; e < E1; e += T) atomicAdd(&cur1[dst1[e]], 1);
    for (int e = tid; e < E2; e += T) atomicAdd(&cur2[dst2[e]], 1);
}

// ---------------- CSR rowptr: scans ----------------
__global__ __launch_bounds__(256) void k_scan_part(
    const int* __restrict__ cur1, int* __restrict__ prt1,
    const int* __restrict__ cur2, int* __restrict__ prt2, int nblk1)
{
    __shared__ int s[256];
    const int tid = threadIdx.x;
    const int l1 = (int)blockIdx.x < nblk1;
    const int b = l1 ? blockIdx.x : blockIdx.x - nblk1;
    const int n = l1 ? N_DST1 : N_DST2;
    const int* deg = l1 ? cur1 : cur2;
    int* part = l1 ? prt1 : prt2;
    const int gid = b * 256 + tid;
    s[tid] = (gid < n) ? deg[gid] : 0;
    __syncthreads();
    for (int off = 128; off > 0; off >>= 1) {
        if (tid < off) s[tid] += s[tid + off];
        __syncthreads();
    }
    if (tid == 0) part[b] = s[0];
}

__global__ __launch_bounds__(512) void k_scan_mid(
    int* __restrict__ prt1, int n1, int* __restrict__ prt2, int n2)
{
    __shared__ int s[512];
    int* p = (blockIdx.x == 0) ? prt1 : prt2;
    const int n = (blockIdx.x == 0) ? n1 : n2;
    const int tid = threadIdx.x;
    const int v = (tid < n) ? p[tid] : 0;
    s[tid] = v;
    __syncthreads();
    for (int off = 1; off < 512; off <<= 1) {
        int t = (tid >= off) ? s[tid - off] : 0;
        __syncthreads();
        s[tid] += t;
        __syncthreads();
    }
    if (tid < n) p[tid] = s[tid] - v;   // exclusive
}

__global__ __launch_bounds__(256) void k_scan_final(
    const int* __restrict__ cur1, int* __restrict__ rp1, const int* __restrict__ prt1,
    const int* __restrict__ cur2, int* __restrict__ rp2, const int* __restrict__ prt2,
    int nblk1)
{
    __shared__ int s[256];
    const int tid = threadIdx.x;
    const int l1 = (int)blockIdx.x < nblk1;
    const int b = l1 ? blockIdx.x : blockIdx.x - nblk1;
    const int n = l1 ? N_DST1 : N_DST2;
    const int* degcur = l1 ? cur1 : cur2;
    int* rowptr = l1 ? rp1 : rp2;
    const int* part = l1 ? prt1 : prt2;
    const int gid = b * 256 + tid;
    const int v = (gid < n) ? degcur[gid] : 0;
    s[tid] = v;
    __syncthreads();
    for (int off = 1; off < 256; off <<= 1) {
        int t = (tid >= off) ? s[tid - off] : 0;
        __syncthreads();
        s[tid] += t;
        __syncthreads();
    }
    const int base = part[b];
    if (gid < n) rowptr[gid] = base + s[tid] - v;
    if (gid == n - 1) rowptr[n] = base + s[tid];
}

// ---------------- radix fill phase A: per-block bin histogram ----------------
__global__ __launch_bounds__(256) void k_hist_bins(
    const int* __restrict__ dst1, int* __restrict__ hist1,
    const int* __restrict__ dst2, int* __restrict__ hist2)
{
    __shared__ int lcnt[NBIN1];
    const int tid = threadIdx.x;
    const bool l1 = blockIdx.x < P1B1;
    const int blk = l1 ? blockIdx.x : blockIdx.x - P1B1;
    const int nbins = l1 ? NBIN1 : NBIN2;
    const int chunk = l1 ? (E1 / P1B1) : (E2 / P1B2);
    const int* dst = l1 ? dst1 : dst2;
    int* hist = l1 ? hist1 : hist2;
    const int e0 = blk * chunk;
    for (int i = tid; i < nbins; i += 256) lcnt[i] = 0;
    __syncthreads();
    for (int i = tid; i < chunk; i += 256)
        atomicAdd(&lcnt[dst[e0 + i] >> 9], 1);
    __syncthreads();
    for (int i = tid; i < nbins; i += 256)
        hist[blk * nbins + i] = lcnt[i];     // coalesced
}

// ---------------- radix fill phase B: per-bin column scan -> offsets ----------------
// offs[blk][bin] = rp[bin*512] + sum_{blk'<blk} hist[blk'][bin]
__global__ __launch_bounds__(256) void k_scan_offs(
    const int* __restrict__ hist1, int* __restrict__ offs1, const int* __restrict__ rp1,
    const int* __restrict__ hist2, int* __restrict__ offs2, const int* __restrict__ rp2)
{
    __shared__ int s[256];
    const int tid = threadIdx.x;
    const bool l1 = blockIdx.x < NBIN1;
    const int b = l1 ? blockIdx.x : blockIdx.x - NBIN1;
    const int nblk = l1 ? P1B1 : P1B2;
    const int nbins = l1 ? NBIN1 : NBIN2;
    const int* hist = l1 ? hist1 : hist2;
    int* offs = l1 ? offs1 : offs2;
    const int base = (l1 ? rp1 : rp2)[b << 9];

    int v[4];
    int lsum = 0;
    #pragma unroll
    for (int j = 0; j < 4; ++j) {
        const int idx = tid * 4 + j;
        v[j] = (idx < nblk) ? hist[idx * nbins + b] : 0;
        lsum += v[j];
    }
    s[tid] = lsum;
    __syncthreads();
    for (int off = 1; off < 256; off <<= 1) {
        int t = (tid >= off) ? s[tid - off] : 0;
        __syncthreads();
        s[tid] += t;
        __syncthreads();
    }
    int run = base + s[tid] - lsum;
    #pragma unroll
    for (int j = 0; j < 4; ++j) {
        const int idx = tid * 4 + j;
        if (idx < nblk) offs[idx * nbins + b] = run;
        run += v[j];
    }
}

// ---------------- radix fill phase C: place (no atomics except LDS) ----------------
// Each block's entries for a bin land at precomputed consecutive slots ->
// contiguous runs, ~2x write amp, full occupancy, zero global atomics.
__global__ __launch_bounds__(256) void k_place(
    const int* __restrict__ src1, const int* __restrict__ dst1,
    const int* __restrict__ offs1, unsigned* __restrict__ stg1,
    const int* __restrict__ src2, const int* __restrict__ dst2,
    const int* __restrict__ offs2, unsigned* __restrict__ stg2)
{
    __shared__ int lcur[NBIN1];
    const int tid = threadIdx.x;
    const bool l1 = blockIdx.x < P1B1;
    const int blk = l1 ? blockIdx.x : blockIdx.x - P1B1;
    const int nbins = l1 ? NBIN1 : NBIN2;
    const int chunk = l1 ? (E1 / P1B1) : (E2 / P1B2);
    const int* src = l1 ? src1 : src2;
    const int* dst = l1 ? dst1 : dst2;
    const int* offs = l1 ? offs1 : offs2;
    unsigned* stg = l1 ? stg1 : stg2;
    const int e0 = blk * chunk;
    for (int i = tid; i < nbins; i += 256) lcur[i] = offs[blk * nbins + i];
    __syncthreads();
    for (int i = tid; i < chunk; i += 256) {
        const int e = e0 + i;
        const int d = dst[e];
        const unsigned pk = ((unsigned)(d & 511) << 19) | (unsigned)src[e];
        const int pos = atomicAdd(&lcur[d >> 9], 1);
        stg[pos] = pk;
    }
}

// ---------------- radix fill phase D: per-bin counting sort into csr ----------------
__global__ __launch_bounds__(256) void k_fill_p2(
    const unsigned* __restrict__ stage1, const int* __restrict__ rp1, int* __restrict__ csr1,
    const unsigned* __restrict__ stage2, const int* __restrict__ rp2, int* __restrict__ csr2)
{
    __shared__ int lcur[512];
    const int tid = threadIdx.x;
    const bool l1 = blockIdx.x < NBIN1;
    const int b = l1 ? blockIdx.x : blockIdx.x - NBIN1;
    const int base = b << 9;
    const int ndst = l1 ? N_DST1 : N_DST2;
    const int nr = min(512, ndst - base);
    const int* rp = l1 ? rp1 : rp2;
    const unsigned* stage = l1 ? stage1 : stage2;
    int* csr = l1 ? csr1 : csr2;

    for (int i = tid; i < nr; i += 256) lcur[i] = rp[base + i];
    __syncthreads();
    const int s0 = rp[base], s1 = rp[base + nr];
    for (int i = s0 + tid; i < s1; i += 256) {
        const unsigned pk = stage[i];
        const int pos = atomicAdd(&lcur[pk >> 19], 1);
        csr[pos] = (int)(pk & 0x7FFFFu);
    }
}

// ---------------- weight packing ----------------
__global__ __launch_bounds__(256) void k_pack(const float* __restrict__ Wa,
                                              const float* __restrict__ Wb,
                                              int Keach, unsigned short* __restrict__ out) {
    const int t = blockIdx.x * 256 + threadIdx.x;
    const int total = (2 * Keach / 32) * 1024;
    if (t >= total) return;
    const int kb = t >> 10;
    const int c  = (t >> 2) & 255;
    const int g  = t & 3;
    const int kbase = kb * 32 + g * 8;
    const float* W = (kbase < Keach) ? (Wa + (size_t)kbase * HID + c)
                                     : (Wb + (size_t)(kbase - Keach) * HID + c);
    unsigned short* o = out + ((size_t)kb * 256 + c) * 32 + g * 8;
    #pragma unroll
    for (int j = 0; j < 8; ++j) o[j] = f2bf(W[(size_t)j * HID]);
}

// ---------------- layer-1 pull (bf16 gather, half-wave per dst) ----------------
__global__ __launch_bounds__(256) void k_pull1(
    const unsigned short* __restrict__ xbf, const int* __restrict__ rp,
    const int* __restrict__ csr, unsigned short* __restrict__ msg)
{
    const int d = blockIdx.x * 8 + (threadIdx.x >> 5);
    const int hl = threadIdx.x & 31;
    const int beg = rp[d], end = rp[d + 1];
    float a0 = 0.f, a1 = 0.f, a2 = 0.f, a3 = 0.f;
    const unsigned short* xb = xbf + hl * 4;
    int j = beg;
    for (; j + 3 < end; j += 4) {
        const int s0 = csr[j], s1 = csr[j + 1], s2 = csr[j + 2], s3 = csr[j + 3];
        const uint2 va = *(const uint2*)(xb + (size_t)s0 * IN_SIZE);
        const uint2 vb = *(const uint2*)(xb + (size_t)s1 * IN_SIZE);
        const uint2 vc = *(const uint2*)(xb + (size_t)s2 * IN_SIZE);
        const uint2 vd = *(const uint2*)(xb + (size_t)s3 * IN_SIZE);
        a0 += (bf2f(va.x) + bf2f(vb.x)) + (bf2f(vc.x) + bf2f(vd.x));
        a1 += (bf2f(va.x >> 16) + bf2f(vb.x >> 16)) + (bf2f(vc.x >> 16) + bf2f(vd.x >> 16));
        a2 += (bf2f(va.y) + bf2f(vb.y)) + (bf2f(vc.y) + bf2f(vd.y));
        a3 += (bf2f(va.y >> 16) + bf2f(vb.y >> 16)) + (bf2f(vc.y >> 16) + bf2f(vd.y >> 16));
    }
    for (; j < end; ++j) {
        const uint2 va = *(const uint2*)(xb + (size_t)csr[j] * IN_SIZE);
        a0 += bf2f(va.x); a1 += bf2f(va.x >> 16);
        a2 += bf2f(va.y); a3 += bf2f(va.y >> 16);
    }
    const float inv = 1.0f / fmaxf((float)(end - beg), 1.0f);
    uint2 o;
    o.x = (unsigned)f2bf(a0 * inv) | ((unsigned)f2bf(a1 * inv) << 16);
    o.y = (unsigned)f2bf(a2 * inv) | ((unsigned)f2bf(a3 * inv) << 16);
    *(uint2*)(msg + (size_t)d * IN_SIZE + hl * 4) = o;
}

// ---------------- layer-1 MFMA GEMM ----------------
__global__ __launch_bounds__(256) void k_gemm1(
    const unsigned short* __restrict__ A1,  // xbf [M][128]
    const unsigned short* __restrict__ A2,  // msg1 [M][128]
    const unsigned short* __restrict__ Wp,
    const float* __restrict__ bias,
    unsigned short* __restrict__ out)       // h bf16 [M][256]
{
    constexpr int NKS = 8;
    const int tid = threadIdx.x;
    const int wid = tid >> 6;
    const int lane = tid & 63;
    const int g = lane >> 4, r16 = lane & 15;
    const int i0 = blockIdx.x * 32;
    const int c0 = wid * 64;

    f32x4 acc[2][4];
    #pragma unroll
    for (int rb = 0; rb < 2; ++rb)
        #pragma unroll
        for (int cf = 0; cf < 4; ++cf)
            acc[rb][cf] = (f32x4){0.f, 0.f, 0.f, 0.f};

    #pragma unroll
    for (int ks = 0; ks < NKS; ++ks) {
        short8 a[2];
        #pragma unroll
        for (int rb = 0; rb < 2; ++rb) {
            const int row = i0 + rb * 16 + r16;
            const int kk = ks * 32 + g * 8;
            a[rb] = (ks < NKS / 2)
                ? *(const short8*)(A1 + (size_t)row * IN_SIZE + kk)
                : *(const short8*)(A2 + (size_t)row * IN_SIZE + (kk - IN_SIZE));
        }
        short8 b[4];
        #pragma unroll
        for (int cf = 0; cf < 4; ++cf) {
            const int col = c0 + cf * 16 + r16;
            b[cf] = *(const short8*)(Wp + ((size_t)ks * 256 + col) * 32 + g * 8);
        }
        #pragma unroll
        for (int rb = 0; rb < 2; ++rb)
            #pragma unroll
            for (int cf = 0; cf < 4; ++cf)
                acc[rb][cf] = __builtin_amdgcn_mfma_f32_16x16x32_bf16(
                    a[rb], b[cf], acc[rb][cf], 0, 0, 0);
    }

    #pragma unroll
    for (int cf = 0; cf < 4; ++cf) {
        const int col = c0 + cf * 16 + r16;
        const float bv = bias[col];
        #pragma unroll
        for (int rb = 0; rb < 2; ++rb)
            #pragma unroll
            for (int rr = 0; rr < 4; ++rr) {
                const int row = i0 + rb * 16 + g * 4 + rr;
                out[(size_t)row * HID + col] = f2bf(fmaxf(acc[rb][cf][rr] + bv, 0.0f));
            }
    }
}

// ---------------- layer-2 fused pull + MFMA GEMM ----------------
__global__ __launch_bounds__(256) void k_sage2(
    const unsigned short* __restrict__ h,   // [N_DST1][256] bf16
    const int* __restrict__ rp, const int* __restrict__ csr,
    const unsigned short* __restrict__ Wp,
    const float* __restrict__ bias,
    float* __restrict__ out)                // [N_DST2][256] f32
{
    __shared__ __align__(16) unsigned short At[32][264];
    const int tid = threadIdx.x;
    const int wid = tid >> 6;
    const int lane = tid & 63;
    const int i0 = blockIdx.x * 32;

    for (int r = 0; r < 8; ++r) {
        const int row = wid * 8 + r;
        const int d = i0 + row;
        const int beg = rp[d], end = rp[d + 1];
        float a0 = 0.f, a1 = 0.f, a2 = 0.f, a3 = 0.f;
        const unsigned short* hb = h + lane * 4;
        int j = beg;
        for (; j + 3 < end; j += 4) {
            const int s0 = csr[j], s1 = csr[j + 1], s2 = csr[j + 2], s3 = csr[j + 3];
            const uint2 va = *(const uint2*)(hb + (size_t)s0 * HID);
            const uint2 vb = *(const uint2*)(hb + (size_t)s1 * HID);
            const uint2 vc = *(const uint2*)(hb + (size_t)s2 * HID);
            const uint2 vd = *(const uint2*)(hb + (size_t)s3 * HID);
            a0 += (bf2f(va.x) + bf2f(vb.x)) + (bf2f(vc.x) + bf2f(vd.x));
            a1 += (bf2f(va.x >> 16) + bf2f(vb.x >> 16)) + (bf2f(vc.x >> 16) + bf2f(vd.x >> 16));
            a2 += (bf2f(va.y) + bf2f(vb.y)) + (bf2f(vc.y) + bf2f(vd.y));
            a3 += (bf2f(va.y >> 16) + bf2f(vb.y >> 16)) + (bf2f(vc.y >> 16) + bf2f(vd.y >> 16));
        }
        for (; j < end; ++j) {
            const uint2 va = *(const uint2*)(hb + (size_t)csr[j] * HID);
            a0 += bf2f(va.x); a1 += bf2f(va.x >> 16);
            a2 += bf2f(va.y); a3 += bf2f(va.y >> 16);
        }
        const float inv = 1.0f / fmaxf((float)(end - beg), 1.0f);
        uint2 o;
        o.x = (unsigned)f2bf(a0 * inv) | ((unsigned)f2bf(a1 * inv) << 16);
        o.y = (unsigned)f2bf(a2 * inv) | ((unsigned)f2bf(a3 * inv) << 16);
        *(uint2*)&At[row][lane * 4] = o;
    }
    __syncthreads();

    const int g = lane >> 4, r16 = lane & 15;
    const int c0 = wid * 64;
    f32x4 acc[2][4];
    #pragma unroll
    for (int rb = 0; rb < 2; ++rb)
        #pragma unroll
        for (int cf = 0; cf < 4; ++cf)
            acc[rb][cf] = (f32x4){0.f, 0.f, 0.f, 0.f};

    #pragma unroll
    for (int ks = 0; ks < 16; ++ks) {
        short8 a[2];
        #pragma unroll
        for (int rb = 0; rb < 2; ++rb) {
            const int row16 = rb * 16 + r16;
            if (ks < 8)
                a[rb] = *(const short8*)(h + (size_t)(i0 + row16) * HID + ks * 32 + g * 8);
            else
                a[rb] = *(const short8*)&At[row16][(ks - 8) * 32 + g * 8];
        }
        short8 b[4];
        #pragma unroll
        for (int cf = 0; cf < 4; ++cf) {
            const int col = c0 + cf * 16 + r16;
            b[cf] = *(const short8*)(Wp + ((size_t)ks * 256 + col) * 32 + g * 8);
        }
        #pragma unroll
        for (int rb = 0; rb < 2; ++rb)
            #pragma unroll
            for (int cf = 0; cf < 4; ++cf)
                acc[rb][cf] = __builtin_amdgcn_mfma_f32_16x16x32_bf16(
                    a[rb], b[cf], acc[rb][cf], 0, 0, 0);
    }

    #pragma unroll
    for (int cf = 0; cf < 4; ++cf) {
        const int col = c0 + cf * 16 + r16;
        const float bv = bias[col];
        #pragma unroll
        for (int rb = 0; rb < 2; ++rb)
            #pragma unroll
            for (int rr = 0; rr < 4; ++rr) {
                const int row = i0 + rb * 16 + g * 4 + rr;
                out[(size_t)row * HID + col] = acc[rb][cf][rr] + bv;
            }
    }
}

extern "C" void kernel_launch(void* const* d_in, const int* in_sizes, int n_in,
                              void* d_out, int out_size, void* d_ws, size_t ws_size,
                              hipStream_t stream) {
    const float* x       = (const float*)d_in[0];
    const int*   src1    = (const int*)d_in[1];
    const int*   dst1    = (const int*)d_in[2];
    const int*   src2    = (const int*)d_in[3];
    const int*   dst2    = (const int*)d_in[4];
    const float* W_self1 = (const float*)d_in[5];
    const float* W_neigh1= (const float*)d_in[6];
    const float* b1      = (const float*)d_in[7];
    const float* W_self2 = (const float*)d_in[8];
    const float* W_neigh2= (const float*)d_in[9];
    const float* b2      = (const float*)d_in[10];
    float* out = (float*)d_out;

    char* ws = (char*)d_ws;
    unsigned short* xbf  = (unsigned short*)(ws + OFF_XBF);
    unsigned short* h    = (unsigned short*)(ws + OFF_H);
    unsigned short* msg1 = (unsigned short*)(ws + OFF_MSG1);
    unsigned* stg1 = (unsigned*)(ws + OFF_STG1);
    unsigned* stg2 = (unsigned*)(ws + OFF_STG2);
    int* hist1 = (int*)(ws + OFF_HIST1);
    int* offs1 = (int*)(ws + OFF_OFFS1);
    int* hist2 = (int*)(ws + OFF_HIST2);
    int* offs2 = (int*)(ws + OFF_OFFS2);
    int* rp1  = (int*)(ws + OFF_RP1);
    int* rp2  = (int*)(ws + OFF_RP2);
    int* cur1 = (int*)(ws + OFF_CUR1);
    int* cur2 = (int*)(ws + OFF_CUR2);
    int* prt1 = (int*)(ws + OFF_PRT1);
    int* prt2 = (int*)(ws + OFF_PRT2);
    int* csr1 = (int*)(ws + OFF_CSR1);
    int* csr2 = (int*)(ws + OFF_CSR2);
    unsigned short* wp1 = (unsigned short*)(ws + OFF_WP1);
    unsigned short* wp2 = (unsigned short*)(ws + OFF_WP2);

    const int nblk1 = (N_DST1 + 255) / 256;   // 391
    const int nblk2 = (N_DST2 + 255) / 256;   // 64

    hipMemsetAsync(cur1, 0, 465536, stream);

    k_pack<<<32, 256, 0, stream>>>(W_self1, W_neigh1, 128, wp1);
    k_pack<<<64, 256, 0, stream>>>(W_self2, W_neigh2, 256, wp2);

    k_hist_bins<<<P1B1 + P1B2, 256, 0, stream>>>(dst1, hist1, dst2, hist2);
    k_prep<<<2048, 256, 0, stream>>>(x, xbf, dst1, cur1, dst2, cur2);
    k_scan_part<<<nblk1 + nblk2, 256, 0, stream>>>(cur1, prt1, cur2, prt2, nblk1);
    k_scan_mid<<<2, 512, 0, stream>>>(prt1, nblk1, prt2, nblk2);
    k_scan_final<<<nblk1 + nblk2, 256, 0, stream>>>(cur1, rp1, prt1, cur2, rp2, prt2, nblk1);
    k_scan_offs<<<NBIN1 + NBIN2, 256, 0, stream>>>(hist1, offs1, rp1, hist2, offs2, rp2);
    k_place<<<P1B1 + P1B2, 256, 0, stream>>>(src1, dst1, offs1, stg1,
                                             src2, dst2, offs2, stg2);
    k_fill_p2<<<NBIN1 + NBIN2, 256, 0, stream>>>(stg1, rp1, csr1, stg2, rp2, csr2);

    k_pull1<<<N_DST1 / 8, 256, 0, stream>>>(xbf, rp1, csr1, msg1);
    k_gemm1<<<N_DST1 / 32, 256, 0, stream>>>(xbf, msg1, wp1, b1, h);
    k_sage2<<<N_DST2 / 32, 256, 0, stream>>>(h, rp2, csr2, wp2, b2, out);
}

// Round 8
// 313.567 us; speedup vs baseline: 4.2253x; 1.1877x over previous
//
#include <hip/hip_runtime.h>

#define IN_SIZE 128
#define HID 256
#define N_SRC1 500000
#define N_DST1 100000
#define E1 1600000
#define N_DST2 16384
#define E2 262144

// radix fill: bins of 512 dst, atomic-free (hist -> offsets -> place -> sort)
#define NBIN1 196          // ceil(100000/512)
#define NBIN2 32           // 16384/512
#define P1B1  800          // layer-1 blocks, chunk = E1/800 = 2000 edges
#define P1B2  256          // layer-2 blocks, chunk = E2/256 = 1024 edges

// ---------------- workspace layout (bytes) ----------------
// xbf [500000][128] bf16 @ 0 (128,000,000)      live: cast -> gemm1
// h   [100000][256] bf16 @ 76,800,000 (51.2MB)  aliases xbf rows 300K..500K
// msg1 [100000][128] bf16 @ 128,000,000 (25.6MB) live: pull1 -> gemm1
//   fill scratch INSIDE msg1 (dead before pull1 writes msg1):
//     stg1 @ +0 (6.4MB), stg2 @ +6.4M (1.05MB)
//     blkpref1 @ +7,448,576 (627,200), blkpref2 @ +8,075,776 (32,768)
//     bintot1 @ +8,108,544, bintot2 @ +8,109,568
//     rpB1 @ +8,109,824 (197 i32), rpB2 @ +8,110,848 (33 i32)
// rp/csr/weights @ 153,600,000; total 162,377,216
#define OFF_XBF  0ull
#define OFF_H    76800000ull
#define OFF_MSG1 128000000ull
#define OFF_STG1 128000000ull
#define OFF_STG2 134400000ull
#define OFF_BP1  135448576ull
#define OFF_BP2  136075776ull
#define OFF_BT1  136108544ull
#define OFF_BT2  136109568ull
#define OFF_RPB1 136109824ull
#define OFF_RPB2 136110848ull
#define OFF_RP1  153600000ull   // [100001] i32 (400,128 alloc)
#define OFF_RP2  154000128ull   // [16385] i32  (65,664 alloc)
#define OFF_CSR1 154535424ull   // [1,600,000] i32 (6,400,000)
#define OFF_CSR2 160935424ull   // [262,144] i32 (1,048,576)
#define OFF_WP1  161984000ull   // packed W1 bf16 (131,072)
#define OFF_WP2  162115072ull   // packed W2 bf16 (262,144)

typedef __attribute__((ext_vector_type(8))) short short8;
typedef __attribute__((ext_vector_type(4))) float f32x4;

__device__ __forceinline__ unsigned short f2bf(float f) {
    unsigned u = __float_as_uint(f);
    return (unsigned short)((u + 0x7FFFu + ((u >> 16) & 1u)) >> 16);
}
__device__ __forceinline__ float bf2f(unsigned short b) {
    return __uint_as_float(((unsigned)b) << 16);
}

// ---------------- pure streaming cast x -> bf16 ----------------
__global__ __launch_bounds__(256) void k_cast(
    const float* __restrict__ x, unsigned short* __restrict__ xbf)
{
    const int T = gridDim.x * 256;
    const int tid = blockIdx.x * 256 + threadIdx.x;
    const float4* x4 = (const float4*)x;
    short8* o8 = (short8*)xbf;
    for (int i = tid; i < N_SRC1 * IN_SIZE / 8; i += T) {
        const float4 u0 = x4[(size_t)i * 2];
        const float4 u1 = x4[(size_t)i * 2 + 1];
        short8 o;
        o[0] = (short)f2bf(u0.x); o[1] = (short)f2bf(u0.y);
        o[2] = (short)f2bf(u0.z); o[3] = (short)f2bf(u0.w);
        o[4] = (short)f2bf(u1.x); o[5] = (short)f2bf(u1.y);
        o[6] = (short)f2bf(u1.z); o[7] = (short)f2bf(u1.w);
        o8[i] = o;
    }
}

// ---------------- radix A: per-block bin histogram ----------------
__global__ __launch_bounds__(256) void k_hist_bins(
    const int* __restrict__ dst1, int* __restrict__ hist1,
    const int* __restrict__ dst2, int* __restrict__ hist2)
{
    __shared__ int lcnt[NBIN1];
    const int tid = threadIdx.x;
    const bool l1 = blockIdx.x < P1B1;
    const int blk = l1 ? blockIdx.x : blockIdx.x - P1B1;
    const int nbins = l1 ? NBIN1 : NBIN2;
    const int chunk = l1 ? (E1 / P1B1) : (E2 / P1B2);
    const int* dst = l1 ? dst1 : dst2;
    int* hist = l1 ? hist1 : hist2;
    const int e0 = blk * chunk;
    for (int i = tid; i < nbins; i += 256) lcnt[i] = 0;
    __syncthreads();
    for (int i = tid; i < chunk; i += 256)
        atomicAdd(&lcnt[dst[e0 + i] >> 9], 1);
    __syncthreads();
    for (int i = tid; i < nbins; i += 256)
        hist[blk * nbins + i] = lcnt[i];     // coalesced
}

// ---------------- radix B1: per-bin block-prefix + bin totals ----------------
// blkpref[blk][bin] = sum_{blk'<blk} hist[blk'][bin];  bintot[bin] = column sum
__global__ __launch_bounds__(256) void k_scan_offs(
    const int* __restrict__ hist1, int* __restrict__ blkpref1, int* __restrict__ bintot1,
    const int* __restrict__ hist2, int* __restrict__ blkpref2, int* __restrict__ bintot2)
{
    __shared__ int s[256];
    const int tid = threadIdx.x;
    const bool l1 = blockIdx.x < NBIN1;
    const int b = l1 ? blockIdx.x : blockIdx.x - NBIN1;
    const int nblk = l1 ? P1B1 : P1B2;
    const int nbins = l1 ? NBIN1 : NBIN2;
    const int* hist = l1 ? hist1 : hist2;
    int* blkpref = l1 ? blkpref1 : blkpref2;
    int* bintot = l1 ? bintot1 : bintot2;

    int v[4];
    int lsum = 0;
    #pragma unroll
    for (int j = 0; j < 4; ++j) {
        const int idx = tid * 4 + j;
        v[j] = (idx < nblk) ? hist[idx * nbins + b] : 0;
        lsum += v[j];
    }
    s[tid] = lsum;
    __syncthreads();
    for (int off = 1; off < 256; off <<= 1) {
        int t = (tid >= off) ? s[tid - off] : 0;
        __syncthreads();
        s[tid] += t;
        __syncthreads();
    }
    int run = s[tid] - lsum;
    #pragma unroll
    for (int j = 0; j < 4; ++j) {
        const int idx = tid * 4 + j;
        if (idx < nblk) blkpref[idx * nbins + b] = run;
        run += v[j];
    }
    if (tid == 255) bintot[b] = s[255];
}

// ---------------- radix B2: exclusive scan of bin totals -> bin-level rowptr ----------------
__global__ __launch_bounds__(256) void k_binscan(
    const int* __restrict__ bt1, int* __restrict__ rpB1,
    const int* __restrict__ bt2, int* __restrict__ rpB2)
{
    __shared__ int s[256];
    const int tid = threadIdx.x;
    const bool l1 = (blockIdx.x == 0);
    const int n = l1 ? NBIN1 : NBIN2;
    const int* bt = l1 ? bt1 : bt2;
    int* rpB = l1 ? rpB1 : rpB2;
    const int v = (tid < n) ? bt[tid] : 0;
    s[tid] = v;
    __syncthreads();
    for (int off = 1; off < 256; off <<= 1) {
        int t = (tid >= off) ? s[tid - off] : 0;
        __syncthreads();
        s[tid] += t;
        __syncthreads();
    }
    if (tid < n) rpB[tid] = s[tid] - v;
    if (tid == n - 1) rpB[n] = s[tid];
}

// ---------------- radix C: place packed entries at precomputed slots ----------------
__global__ __launch_bounds__(256) void k_place(
    const int* __restrict__ src1, const int* __restrict__ dst1,
    const int* __restrict__ blkpref1, const int* __restrict__ rpB1,
    unsigned* __restrict__ stg1,
    const int* __restrict__ src2, const int* __restrict__ dst2,
    const int* __restrict__ blkpref2, const int* __restrict__ rpB2,
    unsigned* __restrict__ stg2)
{
    __shared__ int lcur[NBIN1];
    const int tid = threadIdx.x;
    const bool l1 = blockIdx.x < P1B1;
    const int blk = l1 ? blockIdx.x : blockIdx.x - P1B1;
    const int nbins = l1 ? NBIN1 : NBIN2;
    const int chunk = l1 ? (E1 / P1B1) : (E2 / P1B2);
    const int* src = l1 ? src1 : src2;
    const int* dst = l1 ? dst1 : dst2;
    const int* blkpref = l1 ? blkpref1 : blkpref2;
    const int* rpB = l1 ? rpB1 : rpB2;
    unsigned* stg = l1 ? stg1 : stg2;
    const int e0 = blk * chunk;
    for (int i = tid; i < nbins; i += 256)
        lcur[i] = rpB[i] + blkpref[blk * nbins + i];
    __syncthreads();
    for (int i = tid; i < chunk; i += 256) {
        const int e = e0 + i;
        const int d = dst[e];
        const unsigned pk = ((unsigned)(d & 511) << 19) | (unsigned)src[e];
        const int pos = atomicAdd(&lcur[d >> 9], 1);
        stg[pos] = pk;
    }
}

// ---------------- radix D: per-bin hist -> scan -> rowptr -> counting sort ----------------
__global__ __launch_bounds__(512) void k_fill_p2b(
    const unsigned* __restrict__ stg1, const int* __restrict__ rpB1,
    int* __restrict__ rp1, int* __restrict__ csr1,
    const unsigned* __restrict__ stg2, const int* __restrict__ rpB2,
    int* __restrict__ rp2, int* __restrict__ csr2)
{
    __shared__ int lcnt[512];
    __shared__ int s[512];
    const int tid = threadIdx.x;
    const bool l1 = blockIdx.x < NBIN1;
    const int b = l1 ? blockIdx.x : blockIdx.x - NBIN1;
    const int base = b << 9;
    const int ndst = l1 ? N_DST1 : N_DST2;
    const int nr = min(512, ndst - base);
    const unsigned* stg = l1 ? stg1 : stg2;
    const int* rpB = l1 ? rpB1 : rpB2;
    int* rp = l1 ? rp1 : rp2;
    int* csr = l1 ? csr1 : csr2;
    const int s0 = rpB[b], s1 = rpB[b + 1];

    lcnt[tid] = 0;
    __syncthreads();
    for (int i = s0 + tid; i < s1; i += 512)
        atomicAdd(&lcnt[stg[i] >> 19], 1);
    __syncthreads();

    const int v = lcnt[tid];
    s[tid] = v;
    __syncthreads();
    for (int off = 1; off < 512; off <<= 1) {
        int t = (tid >= off) ? s[tid - off] : 0;
        __syncthreads();
        s[tid] += t;
        __syncthreads();
    }
    const int excl = s0 + s[tid] - v;
    if (tid < nr) rp[base + tid] = excl;
    if (base + tid == ndst - 1) rp[ndst] = s1;
    __syncthreads();
    lcnt[tid] = excl;          // reuse as cursor
    __syncthreads();

    for (int i = s0 + tid; i < s1; i += 512) {
        const unsigned pk = stg[i];
        const int pos = atomicAdd(&lcnt[pk >> 19], 1);
        csr[pos] = (int)(pk & 0x7FFFFu);
    }
}

// ---------------- weight packing ----------------
__global__ __launch_bounds__(256) void k_pack(const float* __restrict__ Wa,
                                              const float* __restrict__ Wb,
                                              int Keach, unsigned short* __restrict__ out) {
    const int t = blockIdx.x * 256 + threadIdx.x;
    const int total = (2 * Keach / 32) * 1024;
    if (t >= total) return;
    const int kb = t >> 10;
    const int c  = (t >> 2) & 255;
    const int g  = t & 3;
    const int kbase = kb * 32 + g * 8;
    const float* W = (kbase < Keach) ? (Wa + (size_t)kbase * HID + c)
                                     : (Wb + (size_t)(kbase - Keach) * HID + c);
    unsigned short* o = out + ((size_t)kb * 256 + c) * 32 + g * 8;
    #pragma unroll
    for (int j = 0; j < 8; ++j) o[j] = f2bf(W[(size_t)j * HID]);
}

// ---------------- layer-1 pull (bf16 gather, half-wave per dst) ----------------
__global__ __launch_bounds__(256) void k_pull1(
    const unsigned short* __restrict__ xbf, const int* __restrict__ rp,
    const int* __restrict__ csr, unsigned short* __restrict__ msg)
{
    const int d = blockIdx.x * 8 + (threadIdx.x >> 5);
    const int hl = threadIdx.x & 31;
    const int beg = rp[d], end = rp[d + 1];
    float a0 = 0.f, a1 = 0.f, a2 = 0.f, a3 = 0.f;
    const unsigned short* xb = xbf + hl * 4;
    int j = beg;
    for (; j + 3 < end; j += 4) {
        const int s0 = csr[j], s1 = csr[j + 1], s2 = csr[j + 2], s3 = csr[j + 3];
        const uint2 va = *(const uint2*)(xb + (size_t)s0 * IN_SIZE);
        const uint2 vb = *(const uint2*)(xb + (size_t)s1 * IN_SIZE);
        const uint2 vc = *(const uint2*)(xb + (size_t)s2 * IN_SIZE);
        const uint2 vd = *(const uint2*)(xb + (size_t)s3 * IN_SIZE);
        a0 += (bf2f(va.x) + bf2f(vb.x)) + (bf2f(vc.x) + bf2f(vd.x));
        a1 += (bf2f(va.x >> 16) + bf2f(vb.x >> 16)) + (bf2f(vc.x >> 16) + bf2f(vd.x >> 16));
        a2 += (bf2f(va.y) + bf2f(vb.y)) + (bf2f(vc.y) + bf2f(vd.y));
        a3 += (bf2f(va.y >> 16) + bf2f(vb.y >> 16)) + (bf2f(vc.y >> 16) + bf2f(vd.y >> 16));
    }
    for (; j < end; ++j) {
        const uint2 va = *(const uint2*)(xb + (size_t)csr[j] * IN_SIZE);
        a0 += bf2f(va.x); a1 += bf2f(va.x >> 16);
        a2 += bf2f(va.y); a3 += bf2f(va.y >> 16);
    }
    const float inv = 1.0f / fmaxf((float)(end - beg), 1.0f);
    uint2 o;
    o.x = (unsigned)f2bf(a0 * inv) | ((unsigned)f2bf(a1 * inv) << 16);
    o.y = (unsigned)f2bf(a2 * inv) | ((unsigned)f2bf(a3 * inv) << 16);
    *(uint2*)(msg + (size_t)d * IN_SIZE + hl * 4) = o;
}

// ---------------- layer-1 MFMA GEMM ----------------
__global__ __launch_bounds__(256) void k_gemm1(
    const unsigned short* __restrict__ A1,  // xbf [M][128]
    const unsigned short* __restrict__ A2,  // msg1 [M][128]
    const unsigned short* __restrict__ Wp,
    const float* __restrict__ bias,
    unsigned short* __restrict__ out)       // h bf16 [M][256]
{
    constexpr int NKS = 8;
    const int tid = threadIdx.x;
    const int wid = tid >> 6;
    const int lane = tid & 63;
    const int g = lane >> 4, r16 = lane & 15;
    const int i0 = blockIdx.x * 32;
    const int c0 = wid * 64;

    f32x4 acc[2][4];
    #pragma unroll
    for (int rb = 0; rb < 2; ++rb)
        #pragma unroll
        for (int cf = 0; cf < 4; ++cf)
            acc[rb][cf] = (f32x4){0.f, 0.f, 0.f, 0.f};

    #pragma unroll
    for (int ks = 0; ks < NKS; ++ks) {
        short8 a[2];
        #pragma unroll
        for (int rb = 0; rb < 2; ++rb) {
            const int row = i0 + rb * 16 + r16;
            const int kk = ks * 32 + g * 8;
            a[rb] = (ks < NKS / 2)
                ? *(const short8*)(A1 + (size_t)row * IN_SIZE + kk)
                : *(const short8*)(A2 + (size_t)row * IN_SIZE + (kk - IN_SIZE));
        }
        short8 b[4];
        #pragma unroll
        for (int cf = 0; cf < 4; ++cf) {
            const int col = c0 + cf * 16 + r16;
            b[cf] = *(const short8*)(Wp + ((size_t)ks * 256 + col) * 32 + g * 8);
        }
        #pragma unroll
        for (int rb = 0; rb < 2; ++rb)
            #pragma unroll
            for (int cf = 0; cf < 4; ++cf)
                acc[rb][cf] = __builtin_amdgcn_mfma_f32_16x16x32_bf16(
                    a[rb], b[cf], acc[rb][cf], 0, 0, 0);
    }

    #pragma unroll
    for (int cf = 0; cf < 4; ++cf) {
        const int col = c0 + cf * 16 + r16;
        const float bv = bias[col];
        #pragma unroll
        for (int rb = 0; rb < 2; ++rb)
            #pragma unroll
            for (int rr = 0; rr < 4; ++rr) {
                const int row = i0 + rb * 16 + g * 4 + rr;
                out[(size_t)row * HID + col] = f2bf(fmaxf(acc[rb][cf][rr] + bv, 0.0f));
            }
    }
}

// ---------------- layer-2 fused pull + MFMA GEMM ----------------
__global__ __launch_bounds__(256) void k_sage2(
    const unsigned short* __restrict__ h,   // [N_DST1][256] bf16
    const int* __restrict__ rp, const int* __restrict__ csr,
    const unsigned short* __restrict__ Wp,
    const float* __restrict__ bias,
    float* __restrict__ out)                // [N_DST2][256] f32
{
    __shared__ __align__(16) unsigned short At[32][264];
    const int tid = threadIdx.x;
    const int wid = tid >> 6;
    const int lane = tid & 63;
    const int i0 = blockIdx.x * 32;

    for (int r = 0; r < 8; ++r) {
        const int row = wid * 8 + r;
        const int d = i0 + row;
        const int beg = rp[d], end = rp[d + 1];
        float a0 = 0.f, a1 = 0.f, a2 = 0.f, a3 = 0.f;
        const unsigned short* hb = h + lane * 4;
        int j = beg;
        for (; j + 3 < end; j += 4) {
            const int s0 = csr[j], s1 = csr[j + 1], s2 = csr[j + 2], s3 = csr[j + 3];
            const uint2 va = *(const uint2*)(hb + (size_t)s0 * HID);
            const uint2 vb = *(const uint2*)(hb + (size_t)s1 * HID);
            const uint2 vc = *(const uint2*)(hb + (size_t)s2 * HID);
            const uint2 vd = *(const uint2*)(hb + (size_t)s3 * HID);
            a0 += (bf2f(va.x) + bf2f(vb.x)) + (bf2f(vc.x) + bf2f(vd.x));
            a1 += (bf2f(va.x >> 16) + bf2f(vb.x >> 16)) + (bf2f(vc.x >> 16) + bf2f(vd.x >> 16));
            a2 += (bf2f(va.y) + bf2f(vb.y)) + (bf2f(vc.y) + bf2f(vd.y));
            a3 += (bf2f(va.y >> 16) + bf2f(vb.y >> 16)) + (bf2f(vc.y >> 16) + bf2f(vd.y >> 16));
        }
        for (; j < end; ++j) {
            const uint2 va = *(const uint2*)(hb + (size_t)csr[j] * HID);
            a0 += bf2f(va.x); a1 += bf2f(va.x >> 16);
            a2 += bf2f(va.y); a3 += bf2f(va.y >> 16);
        }
        const float inv = 1.0f / fmaxf((float)(end - beg), 1.0f);
        uint2 o;
        o.x = (unsigned)f2bf(a0 * inv) | ((unsigned)f2bf(a1 * inv) << 16);
        o.y = (unsigned)f2bf(a2 * inv) | ((unsigned)f2bf(a3 * inv) << 16);
        *(uint2*)&At[row][lane * 4] = o;
    }
    __syncthreads();

    const int g = lane >> 4, r16 = lane & 15;
    const int c0 = wid * 64;
    f32x4 acc[2][4];
    #pragma unroll
    for (int rb = 0; rb < 2; ++rb)
        #pragma unroll
        for (int cf = 0; cf < 4; ++cf)
            acc[rb][cf] = (f32x4){0.f, 0.f, 0.f, 0.f};

    #pragma unroll
    for (int ks = 0; ks < 16; ++ks) {
        short8 a[2];
        #pragma unroll
        for (int rb = 0; rb < 2; ++rb) {
            const int row16 = rb * 16 + r16;
            if (ks < 8)
                a[rb] = *(const short8*)(h + (size_t)(i0 + row16) * HID + ks * 32 + g * 8);
            else
                a[rb] = *(const short8*)&At[row16][(ks - 8) * 32 + g * 8];
        }
        short8 b[4];
        #pragma unroll
        for (int cf = 0; cf < 4; ++cf) {
            const int col = c0 + cf * 16 + r16;
            b[cf] = *(const short8*)(Wp + ((size_t)ks * 256 + col) * 32 + g * 8);
        }
        #pragma unroll
        for (int rb = 0; rb < 2; ++rb)
            #pragma unroll
            for (int cf = 0; cf < 4; ++cf)
                acc[rb][cf] = __builtin_amdgcn_mfma_f32_16x16x32_bf16(
                    a[rb], b[cf], acc[rb][cf], 0, 0, 0);
    }

    #pragma unroll
    for (int cf = 0; cf < 4; ++cf) {
        const int col = c0 + cf * 16 + r16;
        const float bv = bias[col];
        #pragma unroll
        for (int rb = 0; rb < 2; ++rb)
            #pragma unroll
            for (int rr = 0; rr < 4; ++rr) {
                const int row = i0 + rb * 16 + g * 4 + rr;
                out[(size_t)row * HID + col] = acc[rb][cf][rr] + bv;
            }
    }
}

extern "C" void kernel_launch(void* const* d_in, const int* in_sizes, int n_in,
                              void* d_out, int out_size, void* d_ws, size_t ws_size,
                              hipStream_t stream) {
    const float* x       = (const float*)d_in[0];
    const int*   src1    = (const int*)d_in[1];
    const int*   dst1    = (const int*)d_in[2];
    const int*   src2    = (const int*)d_in[3];
    const int*   dst2    = (const int*)d_in[4];
    const float* W_self1 = (const float*)d_in[5];
    const float* W_neigh1= (const float*)d_in[6];
    const float* b1      = (const float*)d_in[7];
    const float* W_self2 = (const float*)d_in[8];
    const float* W_neigh2= (const float*)d_in[9];
    const float* b2      = (const float*)d_in[10];
    float* out = (float*)d_out;

    char* ws = (char*)d_ws;
    unsigned short* xbf  = (unsigned short*)(ws + OFF_XBF);
    unsigned short* h    = (unsigned short*)(ws + OFF_H);
    unsigned short* msg1 = (unsigned short*)(ws + OFF_MSG1);
    unsigned* stg1 = (unsigned*)(ws + OFF_STG1);
    unsigned* stg2 = (unsigned*)(ws + OFF_STG2);
    int* bp1  = (int*)(ws + OFF_BP1);
    int* bp2  = (int*)(ws + OFF_BP2);
    int* bt1  = (int*)(ws + OFF_BT1);
    int* bt2  = (int*)(ws + OFF_BT2);
    int* rpB1 = (int*)(ws + OFF_RPB1);
    int* rpB2 = (int*)(ws + OFF_RPB2);
    int* rp1  = (int*)(ws + OFF_RP1);
    int* rp2  = (int*)(ws + OFF_RP2);
    int* csr1 = (int*)(ws + OFF_CSR1);
    int* csr2 = (int*)(ws + OFF_CSR2);
    unsigned short* wp1 = (unsigned short*)(ws + OFF_WP1);
    unsigned short* wp2 = (unsigned short*)(ws + OFF_WP2);

    k_cast<<<2048, 256, 0, stream>>>(x, xbf);
    k_pack<<<32, 256, 0, stream>>>(W_self1, W_neigh1, 128, wp1);
    k_pack<<<64, 256, 0, stream>>>(W_self2, W_neigh2, 256, wp2);

    k_hist_bins<<<P1B1 + P1B2, 256, 0, stream>>>(dst1, bp1 /*unused yet*/, dst2, bp2);
    // NOTE: hist arrays share storage with blkpref (hist is consumed by
    // k_scan_offs which rewrites blkpref in place via separate buffers below)
    k_scan_offs<<<NBIN1 + NBIN2, 256, 0, stream>>>(bp1, bp1, bt1, bp2, bp2, bt2);
    k_binscan<<<2, 256, 0, stream>>>(bt1, rpB1, bt2, rpB2);
    k_place<<<P1B1 + P1B2, 256, 0, stream>>>(src1, dst1, bp1, rpB1, stg1,
                                             src2, dst2, bp2, rpB2, stg2);
    k_fill_p2b<<<NBIN1 + NBIN2, 512, 0, stream>>>(stg1, rpB1, rp1, csr1,
                                                  stg2, rpB2, rp2, csr2);

    k_pull1<<<N_DST1 / 8, 256, 0, stream>>>(xbf, rp1, csr1, msg1);
    k_gemm1<<<N_DST1 / 32, 256, 0, stream>>>(xbf, msg1, wp1, b1, h);
    k_sage2<<<N_DST2 / 32, 256, 0, stream>>>(h, rp2, csr2, wp2, b2, out);
}